// Round 5
// baseline (337.972 us; speedup 1.0000x reference)
//
#include <hip/hip_runtime.h>
#include <math.h>

// ToyPredictor: h' = tanh(h @ W_hh^T + xt*v + c);  y = h'.W_out + b_out
// v = W_xh @ W_in, c = W_xh @ b_in + b_h  (precomputed on device)
// B=4096, T=512 (511 steps), DIM=128.
//
// Round-5: transposed recurrence (round 4) + FRAGMENT-LINEAR LDS layout
// (round 3's proven conflict-free reads: lane^(lane>>3) bijection onto a
// contiguous 1KiB block per kk). Writes stay 4x ds_write_b64; in this
// layout their bank-pair pattern is exactly 2-way (free, m136).
// Lo-plane via truncation (not RNE): err 2^-16 rel, saves ~16 VALU/step.
//
// S layout: byte(b,k) = (k>>5)*1024 + phys(ln)*16 + (k&7)*2,
//   ln = b + 16*((k>>3)&3), phys = ln ^ (ln>>3).
// Read (b=l15, k=32kk+8lk+e): addr = kk*1024 + (lane^(lane>>3))*16.
// Write (b=l15, k=32wv+16tt+4lk+r): addr = wv*1024 + phys(ln_w)*16
//   + (lk&1)*8 + r*2, ln_w = l15 + 16*(2tt+(lk>>1)).

#define DIM    128
#define TFULL  512
#define TS     511
#define NTHR   256
#define NBLK   256   // 4096 / 16 rows per block
#define SEQPAD 18

typedef __attribute__((ext_vector_type(8))) short short8;
typedef __attribute__((ext_vector_type(4))) float f32x4;

static __device__ __forceinline__ unsigned short bf16_rne(float x) {
  unsigned u = __float_as_uint(x);
  u += 0x7fffu + ((u >> 16) & 1u);
  return (unsigned short)(u >> 16);
}

__global__ void precompute_vc(const float* __restrict__ W_in,
                              const float* __restrict__ b_in,
                              const float* __restrict__ W_xh,
                              const float* __restrict__ b_h,
                              float* __restrict__ ws) {
  const int i = threadIdx.x;   // 128 threads
  float v = 0.f, c = 0.f;
  for (int j = 0; j < DIM; ++j) {
    const float wx = W_xh[i * DIM + j];
    v = fmaf(wx, W_in[j], v);
    c = fmaf(wx, b_in[j], c);
  }
  ws[i] = v;
  ws[DIM + i] = c + b_h[i];
  if (i == 0) ws[2 * DIM] = 0.f;   // zero sse accumulator every launch
}

__global__ __launch_bounds__(NTHR, 1)
void helical_fwd(const float* __restrict__ seq,     // [4096,512]
                 const float* __restrict__ W_hh,    // [128,128]
                 const float* __restrict__ W_out,   // [1,128]
                 const float* __restrict__ b_out,   // [1]
                 const float* __restrict__ ws,      // v[128], c[128]
                 float* __restrict__ sse_accum,     // [1]
                 float* __restrict__ preds) {       // [4096,511]
  __shared__ __align__(16) unsigned short Spl[2][2][2048];   // 16 KiB
  __shared__ __align__(16) float seqT[TFULL * SEQPAD];       // 36 KiB
  __shared__ float yred[2][4][16];

  const int tid  = threadIdx.x;
  const int wv   = tid >> 6;     // wave 0..3 (owns dims 32*wv .. 32*wv+31)
  const int lane = tid & 63;
  const int l15  = lane & 15;    // batch col (C/B layout) / W row (A layout)
  const int lk   = lane >> 4;    // 0..3
  const int row0 = blockIdx.x * 16;
  char* hbB = (char*)Spl;

  // Stage seq transposed: seqT[t*SEQPAD + b] = seq[row0+b][t]
  {
    const float4* src = (const float4*)(seq + (size_t)row0 * TFULL);
#pragma unroll
    for (int k0 = 0; k0 < 8; ++k0) {
      const int k = tid + k0 * NTHR;         // 2048 float4 total
      const float4 v = src[k];
      const int r  = k >> 7;
      const int t0 = (k & 127) << 2;
      seqT[(t0 + 0) * SEQPAD + r] = v.x;
      seqT[(t0 + 1) * SEQPAD + r] = v.y;
      seqT[(t0 + 2) * SEQPAD + r] = v.z;
      seqT[(t0 + 3) * SEQPAD + r] = v.w;
    }
  }
  // S0 = 0: zero buf0 hi+lo (8192 B)
  {
    uint4 z; z.x = z.y = z.z = z.w = 0u;
    ((uint4*)hbB)[tid] = z;
    ((uint4*)hbB)[tid + NTHR] = z;
  }

  // A-frags: W_hh, hi/lo bf16 split. A layout: row = lane&15 (out-dim in
  // tile), k = (lane>>4)*8 + e.  wH[tt][kk][e] = W[32wv+16tt+l15][32kk+8lk+e]
  short8 wH[2][4], wL[2][4];
  float vr[2][4], cr[2][4], wo[2][4];
#pragma unroll
  for (int tt = 0; tt < 2; ++tt) {
    const int rowW = 32 * wv + 16 * tt + l15;
    const float* wr = W_hh + (size_t)rowW * DIM + 8 * lk;
#pragma unroll
    for (int kk = 0; kk < 4; ++kk) {
      float f[8];
      const float4 p0 = *(const float4*)(wr + 32 * kk);
      const float4 p1 = *(const float4*)(wr + 32 * kk + 4);
      f[0] = p0.x; f[1] = p0.y; f[2] = p0.z; f[3] = p0.w;
      f[4] = p1.x; f[5] = p1.y; f[6] = p1.z; f[7] = p1.w;
#pragma unroll
      for (int e = 0; e < 8; ++e) {
        const unsigned short h = bf16_rne(f[e]);
        const float hf = __uint_as_float((unsigned)h << 16);
        wH[tt][kk][e] = (short)h;
        wL[tt][kk][e] = (short)bf16_rne(f[e] - hf);
      }
    }
    const int dbase = 32 * wv + 16 * tt + 4 * lk;   // this lane's 4 dims
#pragma unroll
    for (int r = 0; r < 4; ++r) {
      vr[tt][r] = ws[dbase + r];
      cr[tt][r] = ws[DIM + dbase + r];
      wo[tt][r] = W_out[dbase + r];
    }
  }
  const float bout = b_out[0];

  // Fragment-linear addressing.
  // Reads: contiguous-permuted 16B per lane (proven conflict-free, r3).
  const int rdb = (lane ^ (lane >> 3)) << 4;
  // Writes: 8B slots; bank-pair = (lk0, b0^b3, b1, b2) -> 2-way = free.
  const int lnw0 = l15 | ((lk >> 1) << 4);          // tt=0
  const int lnw1 = l15 | ((2 + (lk >> 1)) << 4);    // tt=1
  const int wB0 = (wv << 10) + ((lnw0 ^ (lnw0 >> 3)) << 4) + ((lk & 1) << 3);
  const int wB1 = (wv << 10) + ((lnw1 ^ (lnw1 >> 3)) << 4) + ((lk & 1) << 3);

  const f32x4 ZERO = {0.f, 0.f, 0.f, 0.f};
  float sse = 0.f;
  int xadr = l15;
  int pidx = (row0 + lane) * TS;   // used by wv0 lanes<16

  __syncthreads();

#define STEP(CUR, DOFIN)                                                       \
  {                                                                            \
    const float xtb = seqT[xadr];                                              \
    xadr += SEQPAD;                                                            \
    if ((DOFIN) && wv == 0 && lane < 16) {  /* finalize y_{t-1} */             \
      const float y = yred[(CUR) ^ 1][0][lane] + yred[(CUR) ^ 1][1][lane]      \
                    + yred[(CUR) ^ 1][2][lane] + yred[(CUR) ^ 1][3][lane]      \
                    + bout;                                                    \
      preds[pidx] = y;                                                         \
      pidx += 1;                                                               \
      const float d = y - xtb;                                                 \
      sse = fmaf(d, d, sse);                                                   \
    }                                                                          \
    short8 sH[4], sL[4];                                                       \
    _Pragma("unroll")                                                          \
    for (int kk = 0; kk < 4; ++kk) {                                           \
      sH[kk] = *(const short8*)(hbB + (CUR)*8192 + kk*1024 + rdb);             \
      sL[kk] = *(const short8*)(hbB + (CUR)*8192 + 4096 + kk*1024 + rdb);      \
    }                                                                          \
    f32x4 p[2], q1[2], q2[2];                                                  \
    _Pragma("unroll")                                                          \
    for (int tt = 0; tt < 2; ++tt) {                                           \
      p[tt][0] = fmaf(xtb, vr[tt][0], cr[tt][0]);                              \
      p[tt][1] = fmaf(xtb, vr[tt][1], cr[tt][1]);                              \
      p[tt][2] = fmaf(xtb, vr[tt][2], cr[tt][2]);                              \
      p[tt][3] = fmaf(xtb, vr[tt][3], cr[tt][3]);                              \
    }                                                                          \
    _Pragma("unroll")                                                          \
    for (int kk = 0; kk < 4; ++kk) {                                           \
      _Pragma("unroll")                                                        \
      for (int tt = 0; tt < 2; ++tt) {                                         \
        p[tt]  = __builtin_amdgcn_mfma_f32_16x16x32_bf16(wH[tt][kk], sH[kk], p[tt], 0, 0, 0); \
        q1[tt] = __builtin_amdgcn_mfma_f32_16x16x32_bf16(wH[tt][kk], sL[kk],  \
                     kk ? q1[tt] : ZERO, 0, 0, 0);                             \
        q2[tt] = __builtin_amdgcn_mfma_f32_16x16x32_bf16(wL[tt][kk], sH[kk],  \
                     kk ? q2[tt] : ZERO, 0, 0, 0);                             \
      }                                                                        \
    }                                                                          \
    float py = 0.f;                                                            \
    _Pragma("unroll")                                                          \
    for (int tt = 0; tt < 2; ++tt) {                                           \
      const f32x4 pre = p[tt] + q1[tt] + q2[tt];                               \
      unsigned uh[4], ur[4];                                                   \
      _Pragma("unroll")                                                        \
      for (int r = 0; r < 4; ++r) {                                            \
        const float pv = pre[r];                                               \
        const float ex = __expf(2.f * pv);                                     \
        const float rc = __builtin_amdgcn_rcpf(ex + 1.f);                      \
        const float th = fmaf(-2.f, rc, 1.f);                                  \
        py = fmaf(th, wo[tt][r], py);                                          \
        uh[r] = __float_as_uint(th);                                           \
        const float hf = __uint_as_float(uh[r] & 0xffff0000u);                 \
        ur[r] = __float_as_uint(th - hf);   /* lo = truncation */              \
      }                                                                        \
      const unsigned h01 = __builtin_amdgcn_perm(uh[1], uh[0], 0x07060302u);   \
      const unsigned h23 = __builtin_amdgcn_perm(uh[3], uh[2], 0x07060302u);   \
      const unsigned l01 = __builtin_amdgcn_perm(ur[1], ur[0], 0x07060302u);   \
      const unsigned l23 = __builtin_amdgcn_perm(ur[3], ur[2], 0x07060302u);   \
      uint2 hv; hv.x = h01; hv.y = h23;                                        \
      uint2 lv; lv.x = l01; lv.y = l23;                                        \
      const int wa = (tt ? wB1 : wB0) + ((CUR) ^ 1) * 8192;                    \
      *(uint2*)(hbB + wa) = hv;                                                \
      *(uint2*)(hbB + wa + 4096) = lv;                                         \
    }                                                                          \
    py += __shfl_xor(py, 16);                                                  \
    py += __shfl_xor(py, 32);                                                  \
    if (lane < 16) yred[(CUR)][wv][lane] = py;                                 \
    asm volatile("s_waitcnt lgkmcnt(0)" ::: "memory");                         \
    __builtin_amdgcn_s_barrier();                                              \
    asm volatile("" ::: "memory");                                             \
  }

  STEP(0, false)                    // t = 0
  for (int tq = 0; tq < 255; ++tq) {
    STEP(1, true)                   // odd t
    STEP(0, true)                   // even t
  }
#undef STEP

  // Tail: finalize y_510 (yred[510&1 = 0]); target seq[b][511] at xadr.
  if (wv == 0) {
    if (lane < 16) {
      const float xf = seqT[xadr];
      const float y = yred[0][0][lane] + yred[0][1][lane]
                    + yred[0][2][lane] + yred[0][3][lane] + bout;
      preds[pidx] = y;
      const float d = y - xf;
      sse = fmaf(d, d, sse);
    }
    float s = (lane < 16) ? sse : 0.f;
    s += __shfl_xor(s, 1);
    s += __shfl_xor(s, 2);
    s += __shfl_xor(s, 4);
    s += __shfl_xor(s, 8);
    if (lane == 0) atomicAdd(sse_accum, s);
  }
}

__global__ void finalize_loss(const float* __restrict__ sse,
                              float* __restrict__ out) {
  out[(size_t)4096 * TS] = sse[0] * (1.0f / (4096.0f * (float)TS));
}

extern "C" void kernel_launch(void* const* d_in, const int* in_sizes, int n_in,
                              void* d_out, int out_size, void* d_ws, size_t ws_size,
                              hipStream_t stream) {
  const float* seq   = (const float*)d_in[0];
  const float* W_in  = (const float*)d_in[1];
  const float* b_in  = (const float*)d_in[2];
  const float* W_hh  = (const float*)d_in[3];
  const float* W_xh  = (const float*)d_in[4];
  const float* b_h   = (const float*)d_in[5];
  const float* W_out = (const float*)d_in[6];
  const float* b_out = (const float*)d_in[7];
  float* out = (float*)d_out;
  float* ws  = (float*)d_ws;   // ws[0..127]=v, ws[128..255]=c, ws[256]=sse

  precompute_vc<<<1, DIM, 0, stream>>>(W_in, b_in, W_xh, b_h, ws);
  helical_fwd<<<NBLK, NTHR, 0, stream>>>(seq, W_hh, W_out, b_out, ws,
                                         ws + 2 * DIM, out);
  finalize_loss<<<1, 1, 0, stream>>>(ws + 2 * DIM, out);
}

// Round 6
// 236.450 us; speedup vs baseline: 1.4294x; 1.4294x over previous
//
#include <hip/hip_runtime.h>
#include <math.h>

// ToyPredictor: h' = tanh(h @ W_hh^T + xt*v + c);  y = h'.W_out + b_out
// v = W_xh @ W_in, c = W_xh @ b_in + b_h  (precomputed on device)
// B=4096, T=512 (511 steps), DIM=128.
//
// Round-6: 8 waves (512 thr), wave w owns one 16-dim tile -> 2 waves/SIMD
// (latency overlap; r5 showed the step is a serial latency chain at 1 wave/
// SIMD). h stored as a SINGLE bf16 plane (RNE): drops the h-lo correction
// term (q1) -> halves reads/writes/epilogue. W keeps hi+lo split (q2 term)
// so W error stays ~2^-17; h-quant error ~2^-9 -> predicted absmax ~0.01
// vs threshold 0.021.
// S layout (fragment-linear, conflict-free reads, r3-proven):
//   byte(b,k) = (k>>5)*1024 + phys(ln)*16 + (k&7)*2,
//   ln = b + 16*((k>>3)&3), phys = ln ^ (ln>>3).
// Read (lane): kk*1024 + (lane^(lane>>3))*16.  Write (wave w): 1x b64 at
//   (w>>1)*1024 + phys(l15+16*(2(w&1)+(lk>>1)))*16 + (lk&1)*8.

#define DIM    128
#define TFULL  512
#define TS     511
#define NTHR   512
#define NBLK   256   // 4096 / 16 rows per block
#define SEQPAD 18

typedef __attribute__((ext_vector_type(8))) short short8;
typedef __attribute__((ext_vector_type(4))) float f32x4;

static __device__ __forceinline__ unsigned short bf16_rne(float x) {
  unsigned u = __float_as_uint(x);
  u += 0x7fffu + ((u >> 16) & 1u);
  return (unsigned short)(u >> 16);
}

__global__ void precompute_vc(const float* __restrict__ W_in,
                              const float* __restrict__ b_in,
                              const float* __restrict__ W_xh,
                              const float* __restrict__ b_h,
                              float* __restrict__ ws) {
  const int i = threadIdx.x;   // 128 threads
  float v = 0.f, c = 0.f;
  for (int j = 0; j < DIM; ++j) {
    const float wx = W_xh[i * DIM + j];
    v = fmaf(wx, W_in[j], v);
    c = fmaf(wx, b_in[j], c);
  }
  ws[i] = v;
  ws[DIM + i] = c + b_h[i];
  if (i == 0) ws[2 * DIM] = 0.f;   // zero sse accumulator every launch
}

__global__ __launch_bounds__(NTHR, 1)
void helical_fwd(const float* __restrict__ seq,     // [4096,512]
                 const float* __restrict__ W_hh,    // [128,128]
                 const float* __restrict__ W_out,   // [1,128]
                 const float* __restrict__ b_out,   // [1]
                 const float* __restrict__ ws,      // v[128], c[128]
                 float* __restrict__ sse_accum,     // [1]
                 float* __restrict__ preds) {       // [4096,511]
  __shared__ __align__(16) unsigned short Sh[2][2048];    // 8 KiB (2 bufs)
  __shared__ __align__(16) float seqT[TFULL * SEQPAD];    // 36 KiB
  __shared__ float yred[2][8][16];

  const int tid  = threadIdx.x;
  const int w    = tid >> 6;     // wave 0..7 (owns dims 16w .. 16w+15)
  const int lane = tid & 63;
  const int l15  = lane & 15;    // batch col
  const int lk   = lane >> 4;    // 0..3
  const int row0 = blockIdx.x * 16;
  char* SB = (char*)Sh;

  // Stage seq transposed: seqT[t*SEQPAD + b] = seq[row0+b][t]
  {
    const float4* src = (const float4*)(seq + (size_t)row0 * TFULL);
#pragma unroll
    for (int k0 = 0; k0 < 4; ++k0) {
      const int k = tid + k0 * NTHR;         // 2048 float4 total
      const float4 v = src[k];
      const int r  = k >> 7;
      const int t0 = (k & 127) << 2;
      seqT[(t0 + 0) * SEQPAD + r] = v.x;
      seqT[(t0 + 1) * SEQPAD + r] = v.y;
      seqT[(t0 + 2) * SEQPAD + r] = v.z;
      seqT[(t0 + 3) * SEQPAD + r] = v.w;
    }
  }
  // S0 = 0: zero buf0 (4096 B = 256 x uint4)
  if (tid < 256) {
    uint4 z; z.x = z.y = z.z = z.w = 0u;
    ((uint4*)SB)[tid] = z;
  }

  // A-frags for tile w: wH/wL[kk][e] = split of W[16w+l15][32kk+8lk+e].
  short8 wH[4], wL[4];
  float vr[4], cr[4], wo[4];
  {
    const int rowW = 16 * w + l15;
    const float* wr = W_hh + (size_t)rowW * DIM + 8 * lk;
#pragma unroll
    for (int kk = 0; kk < 4; ++kk) {
      float f[8];
      const float4 p0 = *(const float4*)(wr + 32 * kk);
      const float4 p1 = *(const float4*)(wr + 32 * kk + 4);
      f[0] = p0.x; f[1] = p0.y; f[2] = p0.z; f[3] = p0.w;
      f[4] = p1.x; f[5] = p1.y; f[6] = p1.z; f[7] = p1.w;
#pragma unroll
      for (int e = 0; e < 8; ++e) {
        const unsigned short h = bf16_rne(f[e]);
        const float hf = __uint_as_float((unsigned)h << 16);
        wH[kk][e] = (short)h;
        wL[kk][e] = (short)bf16_rne(f[e] - hf);
      }
    }
    const int dbase = 16 * w + 4 * lk;   // this lane's 4 output dims
#pragma unroll
    for (int r = 0; r < 4; ++r) {
      vr[r] = ws[dbase + r];
      cr[r] = ws[DIM + dbase + r];
      wo[r] = W_out[dbase + r];
    }
  }
  const float bout = b_out[0];

  // Reads: contiguous-permuted 16B per lane (conflict-free).
  const int rdb = (lane ^ (lane >> 3)) << 4;
  // Write: one 8B slot per lane.
  const int lnw = l15 + 16 * (((w & 1) << 1) | (lk >> 1));
  const int wB  = ((w >> 1) << 10) + ((lnw ^ (lnw >> 3)) << 4) + ((lk & 1) << 3);

  const f32x4 ZERO = {0.f, 0.f, 0.f, 0.f};
  float sse = 0.f;
  int xadr = l15;
  int pidx = (row0 + lane) * TS;   // used by wave0 lanes<16

  __syncthreads();

#define STEP(CUR, DOFIN)                                                       \
  {                                                                            \
    const float xtb = seqT[xadr];                                              \
    xadr += SEQPAD;                                                            \
    if ((DOFIN) && w == 0) {  /* finalize y_{t-1}: sum 8 tile partials */      \
      float part = yred[(CUR) ^ 1][lk][l15] + yred[(CUR) ^ 1][lk + 4][l15];    \
      part += __shfl_xor(part, 16);                                            \
      part += __shfl_xor(part, 32);                                            \
      if (lane < 16) {                                                         \
        const float y = part + bout;                                           \
        preds[pidx] = y;                                                       \
        pidx += 1;                                                             \
        const float d = y - xtb;                                               \
        sse = fmaf(d, d, sse);                                                 \
      }                                                                        \
    }                                                                          \
    short8 sH[4];                                                              \
    _Pragma("unroll")                                                          \
    for (int kk = 0; kk < 4; ++kk)                                             \
      sH[kk] = *(const short8*)(SB + (CUR)*4096 + kk*1024 + rdb);              \
    f32x4 p, q;                                                                \
    p[0] = fmaf(xtb, vr[0], cr[0]);                                            \
    p[1] = fmaf(xtb, vr[1], cr[1]);                                            \
    p[2] = fmaf(xtb, vr[2], cr[2]);                                            \
    p[3] = fmaf(xtb, vr[3], cr[3]);                                            \
    _Pragma("unroll")                                                          \
    for (int kk = 0; kk < 4; ++kk) {                                           \
      p = __builtin_amdgcn_mfma_f32_16x16x32_bf16(wH[kk], sH[kk], p, 0, 0, 0); \
      q = __builtin_amdgcn_mfma_f32_16x16x32_bf16(wL[kk], sH[kk],              \
              kk ? q : ZERO, 0, 0, 0);                                         \
    }                                                                          \
    const f32x4 pre = p + q;                                                   \
    float py = 0.f;                                                            \
    unsigned uh[4];                                                            \
    _Pragma("unroll")                                                          \
    for (int r = 0; r < 4; ++r) {                                              \
      const float pv = pre[r];                                                 \
      const float ex = __expf(2.f * pv);                                       \
      const float rc = __builtin_amdgcn_rcpf(ex + 1.f);                        \
      const float th = fmaf(-2.f, rc, 1.f);                                    \
      py = fmaf(th, wo[r], py);                                                \
      const unsigned u = __float_as_uint(th);                                  \
      uh[r] = u + 0x7fffu + ((u >> 16) & 1u);   /* RNE, take hi16 */           \
    }                                                                          \
    uint2 hv;                                                                  \
    hv.x = __builtin_amdgcn_perm(uh[1], uh[0], 0x07060302u);                   \
    hv.y = __builtin_amdgcn_perm(uh[3], uh[2], 0x07060302u);                   \
    *(uint2*)(SB + ((CUR) ^ 1) * 4096 + wB) = hv;                              \
    py += __shfl_xor(py, 16);                                                  \
    py += __shfl_xor(py, 32);                                                  \
    if (lane < 16) yred[(CUR)][w][lane] = py;                                  \
    asm volatile("s_waitcnt lgkmcnt(0)" ::: "memory");                         \
    __builtin_amdgcn_s_barrier();                                              \
    asm volatile("" ::: "memory");                                             \
  }

  STEP(0, false)                    // t = 0
  for (int tq = 0; tq < 255; ++tq) {
    STEP(1, true)                   // odd t
    STEP(0, true)                   // even t
  }
#undef STEP

  // Tail: finalize y_510 (in yred[510&1 = 0]); target seq[b][511] at xadr.
  if (w == 0) {
    float part = yred[0][lk][l15] + yred[0][lk + 4][l15];
    part += __shfl_xor(part, 16);
    part += __shfl_xor(part, 32);
    if (lane < 16) {
      const float xf = seqT[xadr];
      const float y = part + bout;
      preds[pidx] = y;
      const float d = y - xf;
      sse = fmaf(d, d, sse);
    }
    float s = (lane < 16) ? sse : 0.f;
    s += __shfl_xor(s, 1);
    s += __shfl_xor(s, 2);
    s += __shfl_xor(s, 4);
    s += __shfl_xor(s, 8);
    if (lane == 0) atomicAdd(sse_accum, s);
  }
}

__global__ void finalize_loss(const float* __restrict__ sse,
                              float* __restrict__ out) {
  out[(size_t)4096 * TS] = sse[0] * (1.0f / (4096.0f * (float)TS));
}

extern "C" void kernel_launch(void* const* d_in, const int* in_sizes, int n_in,
                              void* d_out, int out_size, void* d_ws, size_t ws_size,
                              hipStream_t stream) {
  const float* seq   = (const float*)d_in[0];
  const float* W_in  = (const float*)d_in[1];
  const float* b_in  = (const float*)d_in[2];
  const float* W_hh  = (const float*)d_in[3];
  const float* W_xh  = (const float*)d_in[4];
  const float* b_h   = (const float*)d_in[5];
  const float* W_out = (const float*)d_in[6];
  const float* b_out = (const float*)d_in[7];
  float* out = (float*)d_out;
  float* ws  = (float*)d_ws;   // ws[0..127]=v, ws[128..255]=c, ws[256]=sse

  precompute_vc<<<1, DIM, 0, stream>>>(W_in, b_in, W_xh, b_h, ws);
  helical_fwd<<<NBLK, NTHR, 0, stream>>>(seq, W_hh, W_out, b_out, ws,
                                         ws + 2 * DIM, out);
  finalize_loss<<<1, 1, 0, stream>>>(ws + 2 * DIM, out);
}

// Round 7
// 233.070 us; speedup vs baseline: 1.4501x; 1.0145x over previous
//
#include <hip/hip_runtime.h>
#include <math.h>

// ToyPredictor: h' = tanh(h @ W_hh^T + xt*v + c);  y = h'.W_out + b_out
// v = W_xh @ W_in, c = W_xh @ b_in + b_h  (precomputed on device)
// B=4096, T=512 (511 steps), DIM=128.
//
// Round-7 (on r6's 8-wave structure):
//  - y computed on the MFMA pipe: A-frag with W_out (hi+lo) in row 0 against
//    the wave's already-loaded sH (full k=128) -> y lands in C reg0 lanes<16.
//    Kills per-step shfl/yred LDS traffic and the wave-0 straggler.
//  - finalize owner rotates (w == t_pred&7): +8 MFMA amortized across waves.
//  - v_cvt_pk_bf16_f32 packs h' (2 instr vs 12); exp constant folded
//    (e^{2p} = 2^(p*2log2e), one v_mul + v_exp).
// S layout (fragment-linear, conflict-free reads, r3-proven):
//   read: kk*1024 + (lane^(lane>>3))*16;  write: one b64/lane (2-way, free).

#define DIM    128
#define TFULL  512
#define TS     511
#define NTHR   512
#define NBLK   256   // 4096 / 16 rows per block
#define SEQPAD 18

typedef __attribute__((ext_vector_type(8))) short short8;
typedef __attribute__((ext_vector_type(4))) float f32x4;

static __device__ __forceinline__ unsigned short bf16_rne(float x) {
  unsigned u = __float_as_uint(x);
  u += 0x7fffu + ((u >> 16) & 1u);
  return (unsigned short)(u >> 16);
}

__global__ void precompute_vc(const float* __restrict__ W_in,
                              const float* __restrict__ b_in,
                              const float* __restrict__ W_xh,
                              const float* __restrict__ b_h,
                              float* __restrict__ ws) {
  const int i = threadIdx.x;   // 128 threads
  float v = 0.f, c = 0.f;
  for (int j = 0; j < DIM; ++j) {
    const float wx = W_xh[i * DIM + j];
    v = fmaf(wx, W_in[j], v);
    c = fmaf(wx, b_in[j], c);
  }
  ws[i] = v;
  ws[DIM + i] = c + b_h[i];
  if (i == 0) ws[2 * DIM] = 0.f;   // zero sse accumulator every launch
}

__global__ __launch_bounds__(NTHR, 1)
void helical_fwd(const float* __restrict__ seq,     // [4096,512]
                 const float* __restrict__ W_hh,    // [128,128]
                 const float* __restrict__ W_out,   // [1,128]
                 const float* __restrict__ b_out,   // [1]
                 const float* __restrict__ ws,      // v[128], c[128]
                 float* __restrict__ sse_accum,     // [1]
                 float* __restrict__ preds) {       // [4096,511]
  __shared__ __align__(16) unsigned short Sh[2][2048];    // 8 KiB (2 bufs)
  __shared__ __align__(16) float seqT[TFULL * SEQPAD];    // 36 KiB

  const int tid  = threadIdx.x;
  const int w    = tid >> 6;     // wave 0..7 (owns dims 16w .. 16w+15)
  const int lane = tid & 63;
  const int l15  = lane & 15;    // batch col
  const int lk   = lane >> 4;    // 0..3
  const int row0 = blockIdx.x * 16;
  char* SB = (char*)Sh;

  // Stage seq transposed: seqT[t*SEQPAD + b] = seq[row0+b][t]
  {
    const float4* src = (const float4*)(seq + (size_t)row0 * TFULL);
#pragma unroll
    for (int k0 = 0; k0 < 4; ++k0) {
      const int k = tid + k0 * NTHR;         // 2048 float4 total
      const float4 v = src[k];
      const int r  = k >> 7;
      const int t0 = (k & 127) << 2;
      seqT[(t0 + 0) * SEQPAD + r] = v.x;
      seqT[(t0 + 1) * SEQPAD + r] = v.y;
      seqT[(t0 + 2) * SEQPAD + r] = v.z;
      seqT[(t0 + 3) * SEQPAD + r] = v.w;
    }
  }
  // S0 = 0: zero buf0 (4096 B = 256 x uint4)
  if (tid < 256) {
    uint4 z; z.x = z.y = z.z = z.w = 0u;
    ((uint4*)SB)[tid] = z;
  }

  // A-frags for tile w: wH/wL[kk][e] = split of W[16w+l15][32kk+8lk+e].
  short8 wH[4], wL[4];
  float vr[4], cr[4];
  {
    const int rowW = 16 * w + l15;
    const float* wr = W_hh + (size_t)rowW * DIM + 8 * lk;
#pragma unroll
    for (int kk = 0; kk < 4; ++kk) {
      float f[8];
      const float4 p0 = *(const float4*)(wr + 32 * kk);
      const float4 p1 = *(const float4*)(wr + 32 * kk + 4);
      f[0] = p0.x; f[1] = p0.y; f[2] = p0.z; f[3] = p0.w;
      f[4] = p1.x; f[5] = p1.y; f[6] = p1.z; f[7] = p1.w;
#pragma unroll
      for (int e = 0; e < 8; ++e) {
        const unsigned short h = bf16_rne(f[e]);
        const float hf = __uint_as_float((unsigned)h << 16);
        wH[kk][e] = (short)h;
        wL[kk][e] = (short)bf16_rne(f[e] - hf);
      }
    }
    const int dbase = 16 * w + 4 * lk;   // this lane's 4 output dims
#pragma unroll
    for (int r = 0; r < 4; ++r) {
      vr[r] = ws[dbase + r];
      cr[r] = ws[DIM + dbase + r];
    }
  }
  // W_out as A-frag row 0 (hi+lo): every wave carries it (rotating owner).
  short8 woH[4], woL[4];
#pragma unroll
  for (int kk = 0; kk < 4; ++kk) {
#pragma unroll
    for (int e = 0; e < 8; ++e) {
      const float f = (l15 == 0) ? W_out[32 * kk + 8 * lk + e] : 0.f;
      const unsigned short h = bf16_rne(f);
      const float hf = __uint_as_float((unsigned)h << 16);
      woH[kk][e] = (short)h;
      woL[kk][e] = (short)bf16_rne(f - hf);
    }
  }
  const float bout = b_out[0];

  // Reads: contiguous-permuted 16B per lane (conflict-free).
  const int rdb = (lane ^ (lane >> 3)) << 4;
  // Write: one 8B slot per lane (2 lanes/bank-pair = free).
  const int lnw = l15 + 16 * (((w & 1) << 1) | (lk >> 1));
  const int wB  = ((w >> 1) << 10) + ((lnw ^ (lnw >> 3)) << 4) + ((lk & 1) << 3);

  const f32x4 ZERO = {0.f, 0.f, 0.f, 0.f};
  const float K2LOG2E = 2.8853900817779268f;   // 2*log2(e)
  float sse = 0.f;
  int xadr = l15;
  const int pidx_b = (row0 + l15) * TS;

  __syncthreads();

#define STEP(CUR, DOFIN, TPRED)                                                \
  {                                                                            \
    const float xtb = seqT[xadr];                                              \
    xadr += SEQPAD;                                                            \
    short8 sH[4];                                                              \
    _Pragma("unroll")                                                          \
    for (int kk = 0; kk < 4; ++kk)                                             \
      sH[kk] = *(const short8*)(SB + (CUR)*4096 + kk*1024 + rdb);              \
    f32x4 p, q;                                                                \
    p[0] = fmaf(xtb, vr[0], cr[0]);                                            \
    p[1] = fmaf(xtb, vr[1], cr[1]);                                            \
    p[2] = fmaf(xtb, vr[2], cr[2]);                                            \
    p[3] = fmaf(xtb, vr[3], cr[3]);                                            \
    _Pragma("unroll")                                                          \
    for (int kk = 0; kk < 4; ++kk) {                                           \
      p = __builtin_amdgcn_mfma_f32_16x16x32_bf16(wH[kk], sH[kk], p, 0, 0, 0); \
      q = __builtin_amdgcn_mfma_f32_16x16x32_bf16(wL[kk], sH[kk],              \
              kk ? q : ZERO, 0, 0, 0);                                         \
    }                                                                          \
    const bool own = (DOFIN) && (w == ((TPRED) & 7));                          \
    f32x4 y1, y2;                                                              \
    if (own) {                                                                 \
      _Pragma("unroll")                                                        \
      for (int kk = 0; kk < 4; ++kk) {                                         \
        y1 = __builtin_amdgcn_mfma_f32_16x16x32_bf16(woH[kk], sH[kk],          \
                 kk ? y1 : ZERO, 0, 0, 0);                                     \
        y2 = __builtin_amdgcn_mfma_f32_16x16x32_bf16(woL[kk], sH[kk],          \
                 kk ? y2 : ZERO, 0, 0, 0);                                     \
      }                                                                        \
    }                                                                          \
    const f32x4 pre = p + q;                                                   \
    float th[4];                                                               \
    _Pragma("unroll")                                                          \
    for (int r = 0; r < 4; ++r) {                                              \
      const float ag = pre[r] * K2LOG2E;                                       \
      float ex;                                                                \
      asm("v_exp_f32 %0, %1" : "=v"(ex) : "v"(ag));                            \
      const float rc = __builtin_amdgcn_rcpf(ex + 1.f);                        \
      th[r] = fmaf(-2.f, rc, 1.f);                                             \
    }                                                                          \
    uint2 hv;                                                                  \
    asm("v_cvt_pk_bf16_f32 %0, %1, %2" : "=v"(hv.x) : "v"(th[0]), "v"(th[1])); \
    asm("v_cvt_pk_bf16_f32 %0, %1, %2" : "=v"(hv.y) : "v"(th[2]), "v"(th[3])); \
    *(uint2*)(SB + ((CUR) ^ 1) * 4096 + wB) = hv;                              \
    if (own && lane < 16) {                                                    \
      const float y = y1[0] + y2[0] + bout;                                    \
      preds[pidx_b + (TPRED)] = y;                                             \
      const float d = y - xtb;                                                 \
      sse = fmaf(d, d, sse);                                                   \
    }                                                                          \
    asm volatile("s_waitcnt lgkmcnt(0)" ::: "memory");                         \
    __builtin_amdgcn_s_barrier();                                              \
    asm volatile("" ::: "memory");                                             \
  }

  STEP(0, false, 0)                     // iter 0: h0 -> h1, no pred yet
  for (int tq = 0; tq < 255; ++tq) {
    STEP(1, true, 2 * tq)               // iter 2tq+1: pred[2tq]
    STEP(0, true, 2 * tq + 1)           // iter 2tq+2: pred[2tq+1]
  }
#undef STEP

  // Tail: pred[510] from h^(511) (in buf 1); target seq[:,511] at xadr.
  if (w == 6) {   // owner = 510 & 7
    short8 sH[4];
#pragma unroll
    for (int kk = 0; kk < 4; ++kk)
      sH[kk] = *(const short8*)(SB + 4096 + kk * 1024 + rdb);
    f32x4 y1, y2;
#pragma unroll
    for (int kk = 0; kk < 4; ++kk) {
      y1 = __builtin_amdgcn_mfma_f32_16x16x32_bf16(woH[kk], sH[kk],
               kk ? y1 : ZERO, 0, 0, 0);
      y2 = __builtin_amdgcn_mfma_f32_16x16x32_bf16(woL[kk], sH[kk],
               kk ? y2 : ZERO, 0, 0, 0);
    }
    if (lane < 16) {
      const float xf = seqT[xadr];
      const float y = y1[0] + y2[0] + bout;
      preds[pidx_b + 510] = y;
      const float d = y - xf;
      sse = fmaf(d, d, sse);
    }
  }
  // Per-wave sse (lanes 0-15) -> one atomicAdd per wave.
  float s = (lane < 16) ? sse : 0.f;
  s += __shfl_xor(s, 1);
  s += __shfl_xor(s, 2);
  s += __shfl_xor(s, 4);
  s += __shfl_xor(s, 8);
  if (lane == 0) atomicAdd(sse_accum, s);
}

__global__ void finalize_loss(const float* __restrict__ sse,
                              float* __restrict__ out) {
  out[(size_t)4096 * TS] = sse[0] * (1.0f / (4096.0f * (float)TS));
}

extern "C" void kernel_launch(void* const* d_in, const int* in_sizes, int n_in,
                              void* d_out, int out_size, void* d_ws, size_t ws_size,
                              hipStream_t stream) {
  const float* seq   = (const float*)d_in[0];
  const float* W_in  = (const float*)d_in[1];
  const float* b_in  = (const float*)d_in[2];
  const float* W_hh  = (const float*)d_in[3];
  const float* W_xh  = (const float*)d_in[4];
  const float* b_h   = (const float*)d_in[5];
  const float* W_out = (const float*)d_in[6];
  const float* b_out = (const float*)d_in[7];
  float* out = (float*)d_out;
  float* ws  = (float*)d_ws;   // ws[0..127]=v, ws[128..255]=c, ws[256]=sse

  precompute_vc<<<1, DIM, 0, stream>>>(W_in, b_in, W_xh, b_h, ws);
  helical_fwd<<<NBLK, NTHR, 0, stream>>>(seq, W_hh, W_out, b_out, ws,
                                         ws + 2 * DIM, out);
  finalize_loss<<<1, 1, 0, stream>>>(ws + 2 * DIM, out);
}